// Round 2
// baseline (488.398 us; speedup 1.0000x reference)
//
#include <hip/hip_runtime.h>

// out[b,t,u] = h0[b,u] + 0.5f * cumsum_t(x[b,:,u])
// x: (16, 4096, 1024) fp32 -> out same shape. Two-phase chunked scan:
//   t split into 32 chunks of 128; each thread owns one float4 (4 chains)
//   x one chunk. 131072 threads = 2048 waves = 8 waves/CU -> TLP hides HBM
//   latency (round 1's 1-wave/CU ILP design collapsed on vmcnt stalls).
// Phase 1: chunk sums -> partial[c][g] in d_ws (2 MiB).
// Phase 2: prefix from partials (L2-resident) + rescan chunk + write out.

#define B_DIM 16
#define T_DIM 4096
#define U_DIM 1024
#define U4 (U_DIM / 4)        // 256 float4 per row
#define G_DIM (B_DIM * U4)    // 4096 chain-groups
#define CHUNKS 32
#define CLEN (T_DIM / CHUNKS) // 128 t-steps per chunk

typedef float v4f __attribute__((ext_vector_type(4)));

__global__ __launch_bounds__(256) void rac_phase1(
    const v4f* __restrict__ x, v4f* __restrict__ partial) {
  const int tid = blockIdx.x * 256 + threadIdx.x;   // 0..131071
  const int c = tid >> 12;                          // chunk 0..31
  const int g = tid & (G_DIM - 1);                  // chain-group 0..4095
  const int b = g >> 8;
  const int u4 = g & (U4 - 1);

  const v4f* xp = x + ((size_t)b * T_DIM + (size_t)c * CLEN) * U4 + u4;

  v4f s0 = (v4f)0.0f, s1 = (v4f)0.0f;
#pragma unroll 8
  for (int j = 0; j < CLEN; j += 2) {
    v4f a = xp[(size_t)j * U4];
    v4f bbv = xp[(size_t)(j + 1) * U4];
    s0 += a;
    s1 += bbv;
  }
  partial[(size_t)c * G_DIM + g] = s0 + s1;
}

__global__ __launch_bounds__(256) void rac_phase2(
    const v4f* __restrict__ x, const v4f* __restrict__ h0,
    const v4f* __restrict__ partial, v4f* __restrict__ out) {
  const int tid = blockIdx.x * 256 + threadIdx.x;
  const int c = tid >> 12;
  const int g = tid & (G_DIM - 1);
  const int b = g >> 8;
  const int u4 = g & (U4 - 1);

  // Exclusive prefix over preceding chunk sums (c is wave-uniform; partial
  // array is 2 MiB -> L2-resident after phase 1).
  v4f ps = (v4f)0.0f;
  for (int i = 0; i < c; ++i) {
    ps += partial[(size_t)i * G_DIM + g];
  }
  v4f acc = h0[b * U4 + u4] + 0.5f * ps;

  const size_t base = ((size_t)b * T_DIM + (size_t)c * CLEN) * U4 + u4;
  const v4f* xp = x + base;
  v4f* op = out + base;

#pragma unroll 8
  for (int j = 0; j < CLEN; ++j) {
    v4f a = xp[(size_t)j * U4];
    acc += a * 0.5f;  // *0.5f is exact; mul+add == fma here
    __builtin_nontemporal_store(acc, op + (size_t)j * U4);
  }
}

extern "C" void kernel_launch(void* const* d_in, const int* in_sizes, int n_in,
                              void* d_out, int out_size, void* d_ws, size_t ws_size,
                              hipStream_t stream) {
  const v4f* x = (const v4f*)d_in[0];
  const v4f* h0 = (const v4f*)d_in[1];
  v4f* out = (v4f*)d_out;
  v4f* partial = (v4f*)d_ws;  // CHUNKS * G_DIM * 16 B = 2 MiB

  const int threads = G_DIM * CHUNKS;  // 131072
  dim3 block(256);
  dim3 grid(threads / 256);  // 512 blocks

  rac_phase1<<<grid, block, 0, stream>>>(x, partial);
  rac_phase2<<<grid, block, 0, stream>>>(x, h0, partial, out);
}

// Round 3
// 484.064 us; speedup vs baseline: 1.0090x; 1.0090x over previous
//
#include <hip/hip_runtime.h>

// out[b,t,u] = h0[b,u] + 0.5f * cumsum_t(x[b,:,u])
// x: (16, 4096, 1024) fp32 -> out same shape.
//
// Two-phase chunked scan, t split into 64 chunks of 64:
//   262144 threads = 4096 waves = 16 waves/CU (TLP covers vmcnt store-ack
//   stalls that serialized the round-1 single-wave design).
// Phase 1: per-thread chunk sums -> partial[c][g] in d_ws (4 MiB, cached).
// Phase 2: exclusive prefix over partials (L2/L3-hot) + rescan chunk + write.
//   x (256 MiB) fits the 256 MiB Infinity Cache; out uses nontemporal stores
//   so phase-2 x reads hit L3 instead of HBM.
// Inner loops: batched loads THEN batched fma+store, so the one load-wait per
// batch is emitted before any stores enter the vmcnt queue.

#define B_DIM 16
#define T_DIM 4096
#define U_DIM 1024
#define U4 (U_DIM / 4)        // 256 float4 per (b,t) row
#define G_DIM (B_DIM * U4)    // 4096 chain-groups
#define CHUNKS 64
#define CLEN (T_DIM / CHUNKS) // 64 t-steps per chunk

typedef float v4f __attribute__((ext_vector_type(4)));

__global__ __launch_bounds__(256) void rac_phase1(
    const v4f* __restrict__ x, v4f* __restrict__ partial) {
  const int tid = blockIdx.x * 256 + threadIdx.x;   // 0..262143
  const int c = tid >> 12;                          // chunk 0..63 (block-uniform)
  const int g = tid & (G_DIM - 1);                  // chain-group 0..4095
  const int b = g >> 8;
  const int u4 = g & (U4 - 1);

  const v4f* xp = x + ((size_t)b * T_DIM + (size_t)c * CLEN) * U4 + u4;

  v4f s0 = (v4f)0.0f, s1 = (v4f)0.0f;
  for (int j = 0; j < CLEN; j += 8) {
    v4f v[8];
#pragma unroll
    for (int i = 0; i < 8; ++i) v[i] = xp[(size_t)(j + i) * U4];
#pragma unroll
    for (int i = 0; i < 8; i += 2) {
      s0 += v[i];
      s1 += v[i + 1];
    }
  }
  partial[(size_t)c * G_DIM + g] = s0 + s1;  // cached store: phase 2 reads it
}

__global__ __launch_bounds__(256) void rac_phase2(
    const v4f* __restrict__ x, const v4f* __restrict__ h0,
    const v4f* __restrict__ partial, v4f* __restrict__ out) {
  const int tid = blockIdx.x * 256 + threadIdx.x;
  const int c = tid >> 12;                          // block-uniform
  const int g = tid & (G_DIM - 1);
  const int b = g >> 8;
  const int u4 = g & (U4 - 1);

  // Exclusive prefix of preceding chunk sums (4 MiB array, L2/L3-hot).
  v4f ps = (v4f)0.0f;
  for (int i = 0; i < c; ++i) {
    ps += partial[(size_t)i * G_DIM + g];
  }
  v4f acc = h0[b * U4 + u4] + 0.5f * ps;

  const size_t base = ((size_t)b * T_DIM + (size_t)c * CLEN) * U4 + u4;
  const v4f* xp = x + base;
  v4f* op = out + base;

  for (int j = 0; j < CLEN; j += 16) {
    v4f v[16];
#pragma unroll
    for (int i = 0; i < 16; ++i) v[i] = xp[(size_t)(j + i) * U4];
    // One vmcnt wait lands here, before any store is outstanding.
#pragma unroll
    for (int i = 0; i < 16; ++i) {
      acc += v[i] * 0.5f;  // *0.5f exact; matches h0 + 0.5*cumsum
      __builtin_nontemporal_store(acc, op + (size_t)(j + i) * U4);
    }
  }
}

extern "C" void kernel_launch(void* const* d_in, const int* in_sizes, int n_in,
                              void* d_out, int out_size, void* d_ws, size_t ws_size,
                              hipStream_t stream) {
  const v4f* x = (const v4f*)d_in[0];
  const v4f* h0 = (const v4f*)d_in[1];
  v4f* out = (v4f*)d_out;
  v4f* partial = (v4f*)d_ws;  // CHUNKS * G_DIM * 16 B = 4 MiB

  const int threads = G_DIM * CHUNKS;  // 262144
  dim3 block(256);
  dim3 grid(threads / 256);            // 1024 blocks

  rac_phase1<<<grid, block, 0, stream>>>(x, partial);
  rac_phase2<<<grid, block, 0, stream>>>(x, h0, partial, out);
}